// Round 8
// baseline (323.645 us; speedup 1.0000x reference)
//
#include <hip/hip_runtime.h>

// Problem constants
constexpr int NROWS     = 32;
constexpr int HW        = 768 * 768;        // 589824 pixels per image
constexpr int CHUNKS    = 64;               // chunks per row in main pass
constexpr int CHUNK_PIX = HW / CHUNKS;      // 9216
constexpr int NB        = 4096;             // buckets over sortable margin bits
constexpr int THREADS   = 256;

// Workspace layout (bytes)
// META (zeroed each call): gTicket u32 @0; rowTicket u32[32] @64; rowCfx u64[32] @256;
//                          rowr01 double[2] @512
constexpr size_t OFF_META    = 0;
constexpr size_t OFF_ROWPART = 8192;       // float[2*CHUNKS] (rows 0,1 only; fully written each call)
constexpr size_t OFF_HIST    = 16384;      // u64[NROWS*NB] = 1 MiB (zeroed each call)
constexpr size_t ZERO_META   = 8192;

// Zero meta + packed histogram. Grid covers meta (8 KB) + hist (1 MiB) = 258*256*16 B.
__global__ __launch_bounds__(256) void zero_kernel(ulonglong2* __restrict__ m,
                                                   ulonglong2* __restrict__ h)
{
    const size_t i = (size_t)blockIdx.x * 256 + threadIdx.x;
    if (i < ZERO_META / 16) m[i] = ulonglong2{0ull, 0ull};
    else h[i - ZERO_META / 16] = ulonglong2{0ull, 0ull};
}

// Single fused kernel: per (row, chunk) block streams its chunk (branch-free:
// sortable-margin-bit bucketing, packed LDS histogram atomics), flushes to the
// row's global histogram, then the LAST block of each row (ticket) re-reads the
// row histogram from L2 and performs the top-k selection; the last row overall
// (global ticket) writes the scalar output.
//   ub  = bits(x0-x1) ^ (t<<31)        margin v; ce is monotone-DECREASING in v
//   key = sortable(ub) >> 20           4096 buckets ascending in v
//   B   = k smallest margins = k largest ce;  k = min(pos, HW-pos)
//   Cr  = |A ∪ B| = 2k - (#positives in B)   (A = top-k positives ⊂ B ∪ positives)
__global__ __launch_bounds__(THREADS) void ce_hist_kernel(
    const float* __restrict__ logits, const int* __restrict__ targets,
    float* __restrict__ rowpart, unsigned long long* __restrict__ hist,
    unsigned* __restrict__ gTicket, unsigned* __restrict__ rowTicket,
    unsigned long long* __restrict__ rowCfx, double* __restrict__ rowr01,
    float* __restrict__ outp)
{
    __shared__ unsigned            lh[NB];
    __shared__ float               redf[THREADS / 64];
    __shared__ unsigned long long  sc[THREADS];
    __shared__ int                 s_win;

    const int tid   = threadIdx.x;
    const int blk   = blockIdx.x;
    const int row   = blk >> 6;      // / CHUNKS
    const int chunk = blk & 63;      // % CHUNKS

    for (int b = tid; b < NB; b += THREADS) lh[b] = 0u;
    __syncthreads();

    const float* x0 = logits + (size_t)row * 2 * HW + (size_t)chunk * CHUNK_PIX;
    const float* x1 = x0 + HW;
    const int*   tp = targets + (size_t)row * HW + (size_t)chunk * CHUNK_PIX;
    const bool needsum = (row < 2);

    float lsum = 0.f;

    for (int p = tid * 4; p < CHUNK_PIX; p += THREADS * 4) {
        const float4 a0 = *(const float4*)(x0 + p);
        const float4 a1 = *(const float4*)(x1 + p);
        const int4   t4 = *(const int4*)(tp + p);
        const float* v0 = (const float*)&a0;
        const float* v1 = (const float*)&a1;
        const int*   tv = (const int*)&t4;
#pragma unroll
        for (int j = 0; j < 4; ++j) {
            const unsigned t  = (unsigned)tv[j];
            const unsigned ub = __float_as_uint(v0[j] - v1[j]) ^ (t << 31); // margin bits
            if (needsum) {   // rows 0,1 only: ce2 = max(-w,0) + log2(1+2^-|w|)
                const float w = __uint_as_float(ub) * 1.4426950408889634f;
                lsum += fmaxf(-w, 0.f) + __log2f(1.f + exp2f(-fabsf(w)));
            }
            const unsigned m   = (unsigned)((int)ub >> 31) | 0x80000000u;   // sortable xform
            const unsigned key = (ub ^ m) >> 20;
            atomicAdd(&lh[key], 1u | (t << 16));
        }
    }

    if (needsum) {  // deterministic per-chunk ce2 partial (rows 0,1 only)
        for (int o = 32; o > 0; o >>= 1) lsum += __shfl_down(lsum, o);
        if ((tid & 63) == 0) redf[tid >> 6] = lsum;
    }
    __syncthreads();   // orders LDS histogram atomics before flush
    if (needsum && tid == 0) {
        float s = 0.f;
        for (int w = 0; w < THREADS / 64; ++w) s += redf[w];
        rowpart[row * CHUNKS + chunk] = s;
    }

    // flush packed histogram: one u64 device-scope atomic per nonzero bucket
    // (hi32 = all count, lo32 = positives count)
    for (int b = tid; b < NB; b += THREADS) {
        const unsigned v = lh[b];
        if (v) {
            atomicAdd(&hist[(size_t)row * NB + b],
                      ((unsigned long long)(v & 0xFFFFu) << 32) | (v >> 16));
        }
    }

    __threadfence();       // release this block's hist/rowpart writes
    __syncthreads();       // per-wave vmcnt drain: all flush atomics complete
    if (tid == 0) {
        const unsigned old = __hip_atomic_fetch_add(&rowTicket[row], 1u,
                                 __ATOMIC_ACQ_REL, __HIP_MEMORY_SCOPE_AGENT);
        s_win = (old == CHUNKS - 1);
    }
    __syncthreads();
    if (!s_win) return;

    // ---------- last block of this row: selection ----------
    __threadfence();       // acquire: see all 64 blocks' contributions
    const unsigned long long* rh = hist + (size_t)row * NB;
    const int base = tid * 16;
    unsigned ssum = 0u, psum = 0u;
    for (int j = 0; j < 16; ++j) {
        const unsigned long long v = __hip_atomic_load(&rh[base + j],
                                         __ATOMIC_RELAXED, __HIP_MEMORY_SCOPE_AGENT);
        ssum += (unsigned)(v >> 32);
        psum += (unsigned)v;
    }
    sc[tid] = ((unsigned long long)ssum << 32) | psum;
    __syncthreads();

    // inclusive Hillis-Steele scan (no cross-carry: both fields < 2^32)
#pragma unroll
    for (int off = 1; off < 256; off <<= 1) {
        const unsigned long long v = sc[tid];
        const unsigned long long a = (tid >= off) ? sc[tid - off] : 0ull;
        __syncthreads();
        sc[tid] = v + a;
        __syncthreads();
    }

    const unsigned pos   = (unsigned)sc[255];
    const unsigned k     = min(pos, (unsigned)HW - pos);
    const unsigned long long incl = sc[tid];
    const unsigned cexcl = (unsigned)(incl >> 32) - ssum;
    const unsigned pexcl = (unsigned)incl - psum;

    if (k > 0 && cexcl < k && cexcl + ssum >= k) {     // exactly one thread matches
        unsigned cum = cexcl, pp = pexcl;
        for (int j = 0; j < 16; ++j) {
            const unsigned long long v = __hip_atomic_load(&rh[base + j],
                                             __ATOMIC_RELAXED, __HIP_MEMORY_SCOPE_AGENT);
            const unsigned hb  = (unsigned)(v >> 32);
            const unsigned phb = (unsigned)v;
            const unsigned nv  = cum + hb;
            if (nv >= k) {
                const unsigned rneed = k - cum;        // 1..hb
                const double P  = (double)pp +
                                  (hb ? (double)rneed * (double)phb / (double)hb : 0.0);
                const double Cr = 2.0 * (double)k - P; // |A ∪ B| for this row
                __hip_atomic_store(&rowCfx[row],
                                   (unsigned long long)(Cr * 1048576.0 + 0.5),
                                   __ATOMIC_RELAXED, __HIP_MEMORY_SCOPE_AGENT);
                break;
            }
            cum = nv;
            pp += phb;
        }
    }
    // (k == 0: rowCfx stays 0 from the zero pass -> contributes nothing)

    // rows 0,1: reduce the 64 deterministic chunk partials
    if (row < 2 && tid < 64) {
        float f = __hip_atomic_load(&rowpart[row * CHUNKS + tid],
                                    __ATOMIC_RELAXED, __HIP_MEMORY_SCOPE_AGENT);
        double d = (double)f;
        for (int o = 32; o > 0; o >>= 1) d += __shfl_down(d, o);
        if (tid == 0)
            __hip_atomic_store(&rowr01[row], d,
                               __ATOMIC_RELAXED, __HIP_MEMORY_SCOPE_AGENT);
    }

    __threadfence();
    __syncthreads();       // all selection writes complete before the global ticket
    if (tid == 0) {
        const unsigned g = __hip_atomic_fetch_add(gTicket, 1u,
                               __ATOMIC_ACQ_REL, __HIP_MEMORY_SCOPE_AGENT);
        if (g == NROWS - 1) {            // ---------- final scalar ----------
            __threadfence();
            double C = 0.0;
            for (int r = 0; r < NROWS; ++r)
                C += (double)__hip_atomic_load(&rowCfx[r],
                         __ATOMIC_RELAXED, __HIP_MEMORY_SCOPE_AGENT);
            C *= (1.0 / 1048576.0);
            const double t0 = __hip_atomic_load(&rowr01[0],
                                  __ATOMIC_RELAXED, __HIP_MEMORY_SCOPE_AGENT);
            const double t1 = __hip_atomic_load(&rowr01[1],
                                  __ATOMIC_RELAXED, __HIP_MEMORY_SCOPE_AGENT);
            constexpr double LN2 = 0.6931471805599453;
            const double nL = (double)NROWS * (double)HW;
            const double r0 = t0 / (double)HW * LN2;
            const double r1 = t1 / (double)HW * LN2;
            outp[0] = (float)(((nL - C) * r0 + C * r1) / nL);
        }
    }
}

extern "C" void kernel_launch(void* const* d_in, const int* in_sizes, int n_in,
                              void* d_out, int out_size, void* d_ws, size_t ws_size,
                              hipStream_t stream) {
    const float* logits  = (const float*)d_in[0];
    const int*   targets = (const int*)d_in[1];
    float*       out     = (float*)d_out;
    char*        ws      = (char*)d_ws;

    constexpr size_t HIST_BYTES = (size_t)NROWS * NB * 8;     // 1 MiB
    constexpr int    ZBLOCKS    = (int)((ZERO_META + HIST_BYTES) / (256 * 16)); // 258

    zero_kernel<<<ZBLOCKS, 256, 0, stream>>>(
        (ulonglong2*)(ws + OFF_META), (ulonglong2*)(ws + OFF_HIST));

    ce_hist_kernel<<<NROWS * CHUNKS, THREADS, 0, stream>>>(
        logits, targets,
        (float*)(ws + OFF_ROWPART),
        (unsigned long long*)(ws + OFF_HIST),
        (unsigned*)(ws + OFF_META),              // gTicket
        (unsigned*)(ws + OFF_META + 64),         // rowTicket[32]
        (unsigned long long*)(ws + OFF_META + 256),  // rowCfx[32]
        (double*)(ws + OFF_META + 512),          // rowr01[2]
        out);
}

// Round 10
// 55.959 us; speedup vs baseline: 5.7836x; 5.7836x over previous
//
#include <hip/hip_runtime.h>

// Problem constants
constexpr int NROWS     = 32;
constexpr int HW        = 768 * 768;        // 589824 pixels per image
constexpr int CHUNKS    = 64;               // chunks per row in main pass
constexpr int CHUNK_PIX = HW / CHUNKS;      // 9216
constexpr int NB        = 4096;             // buckets over sortable margin bits
constexpr int THREADS   = 256;

// clang ext-vector types: accepted by __builtin_nontemporal_load (HIP_vector_type is not)
typedef float evf4 __attribute__((ext_vector_type(4)));
typedef int   evi4 __attribute__((ext_vector_type(4)));

// Workspace layout (bytes)
constexpr size_t OFF_ROWPART = 0;          // float[NROWS*CHUNKS] = 8 KB (fully overwritten each call)
constexpr size_t OFF_META    = 8192;       // zeroed: ticket u32 @0; rowCfx u64[32] @64; rowr01 double[2] @320
constexpr size_t OFF_HIST    = 16384;      // u64[NROWS*NB] = 1 MiB (zeroed)
constexpr size_t ZERO_LEN    = 8192 + (size_t)NROWS * NB * 8;   // 1056768 = 258*256*16

// Zero meta + packed histogram: 258 blocks x 256 threads x 16 B.
__global__ __launch_bounds__(256) void zero_kernel(ulonglong2* __restrict__ h)
{
    h[(size_t)blockIdx.x * 256 + threadIdx.x] = ulonglong2{0ull, 0ull};
}

// Pass 1: per (row, chunk) block. Branch-free streaming body with NON-TEMPORAL
// loads (one-touch streaming data, evict-first):
//   ub  = bits(x0-x1) ^ (t<<31)                  (margin v; ce monotone-decreasing in v)
//   key = sortable(ub) >> 20                     (4096 buckets, ascending in v)
//   packed LDS atomic: low16 = all, high16 = positives (block px = 9216 < 2^16)
// ce2 (= ce/ln2) sums only for rows 0,1 (block-uniform branch) — all the output needs.
__global__ __launch_bounds__(THREADS) void ce_hist_kernel(
    const float* __restrict__ logits, const int* __restrict__ targets,
    float* __restrict__ rowpart, unsigned long long* __restrict__ hist)
{
    __shared__ unsigned lh[NB];
    __shared__ float    redf[THREADS / 64];

    const int blk   = blockIdx.x;
    const int row   = blk >> 6;      // / CHUNKS
    const int chunk = blk & 63;      // % CHUNKS

    for (int b = threadIdx.x; b < NB; b += THREADS) lh[b] = 0u;
    __syncthreads();

    const float* x0 = logits + (size_t)row * 2 * HW + (size_t)chunk * CHUNK_PIX;
    const float* x1 = x0 + HW;
    const int*   tp = targets + (size_t)row * HW + (size_t)chunk * CHUNK_PIX;
    const bool needsum = (row < 2);

    float lsum = 0.f;

    for (int p = threadIdx.x * 4; p < CHUNK_PIX; p += THREADS * 4) {
        const evf4 a0 = __builtin_nontemporal_load((const evf4*)(x0 + p));
        const evf4 a1 = __builtin_nontemporal_load((const evf4*)(x1 + p));
        const evi4 t4 = __builtin_nontemporal_load((const evi4*)(tp + p));
#pragma unroll
        for (int j = 0; j < 4; ++j) {
            const unsigned t  = (unsigned)t4[j];
            const unsigned ub = __float_as_uint(a0[j] - a1[j]) ^ (t << 31); // margin bits
            if (needsum) {   // rows 0,1 only: ce2 = max(-w,0) + log2(1+2^-|w|)
                const float w = __uint_as_float(ub) * 1.4426950408889634f;
                lsum += fmaxf(-w, 0.f) + __log2f(1.f + exp2f(-fabsf(w)));
            }
            // sortable float transform: ascending key <=> ascending margin v
            const unsigned m   = (unsigned)((int)ub >> 31) | 0x80000000u;
            const unsigned key = (ub ^ m) >> 20;
            atomicAdd(&lh[key], 1u | (t << 16));
        }
    }

    // wave-reduce the ce2 sum
    for (int o = 32; o > 0; o >>= 1) lsum += __shfl_down(lsum, o);
    const int wid  = threadIdx.x >> 6;
    const int lane = threadIdx.x & 63;
    if (lane == 0) redf[wid] = lsum;
    __syncthreads();   // also orders all LDS histogram atomics before flush

    if (threadIdx.x == 0) {
        float s = 0.f;
        for (int w = 0; w < THREADS / 64; ++w) s += redf[w];
        rowpart[row * CHUNKS + chunk] = s;   // deterministic partial (0 for rows >= 2)
    }

    // flush packed histogram: one u64 global atomic per nonzero bucket
    for (int b = threadIdx.x; b < NB; b += THREADS) {
        const unsigned v = lh[b];
        if (v) {
            atomicAdd(&hist[(size_t)row * NB + b],
                      ((unsigned long long)(v & 0xFFFFu) << 32) | (v >> 16));
        }
    }
}

// Pass 2 (fused select + final): one block per row.
// pos = total positives; k = min(pos, HW-pos); B = k smallest margins (= k largest ce).
// Packed u64 Hillis-Steele scan (counts hi32, positives lo32) finds the threshold
// bucket + positives below it; proportional split inside it.
// Cr = |A ∪ B| = 2k - (#positives in B), stored fixed-point x2^20 (exact, deterministic).
// The last block (atomic ticket) reduces all rows and writes the scalar output.
__global__ __launch_bounds__(256) void select_kernel(
    const unsigned long long* __restrict__ hist,
    const float* __restrict__ rowpart,
    unsigned* __restrict__ ticket,
    unsigned long long* __restrict__ rowCfx,
    double* __restrict__ rowr01,
    float* __restrict__ outp)
{
    __shared__ unsigned lh[NB];
    __shared__ unsigned lph[NB];
    __shared__ unsigned long long sc[256];
    __shared__ unsigned long long s_crfx;
    __shared__ double s_rsum;

    const int row = blockIdx.x;
    const int tid = threadIdx.x;

    for (int b = tid; b < NB; b += 256) {
        const unsigned long long v = hist[(size_t)row * NB + b];
        lh[b]  = (unsigned)(v >> 32);   // all
        lph[b] = (unsigned)v;           // positives
    }
    if (tid == 0) s_crfx = 0ull;
    __syncthreads();

    // per-thread 16-bucket segment sums, packed
    const int base = tid * 16;
    unsigned ssum = 0u, psum = 0u;
#pragma unroll
    for (int j = 0; j < 16; ++j) { ssum += lh[base + j]; psum += lph[base + j]; }
    sc[tid] = ((unsigned long long)ssum << 32) | psum;
    __syncthreads();

    // inclusive Hillis-Steele scan over 256 threads (no cross-carry: both sums < 2^32)
#pragma unroll
    for (int off = 1; off < 256; off <<= 1) {
        const unsigned long long v = sc[tid];
        const unsigned long long a = (tid >= off) ? sc[tid - off] : 0ull;
        __syncthreads();
        sc[tid] = v + a;
        __syncthreads();
    }

    const unsigned pos   = (unsigned)sc[255];          // total positives
    const unsigned k     = min(pos, (unsigned)HW - pos);
    const unsigned long long incl = sc[tid];
    const unsigned cexcl = (unsigned)(incl >> 32) - ssum;
    const unsigned pexcl = (unsigned)incl - psum;

    if (k > 0 && cexcl < k && cexcl + ssum >= k) {     // exactly one thread matches
        unsigned cum = cexcl, pp = pexcl;
#pragma unroll
        for (int j = 0; j < 16; ++j) {
            const int b = base + j;
            const unsigned nv = cum + lh[b];
            if (nv >= k) {
                const unsigned rneed = k - cum;        // 1..lh[b]
                const unsigned hb = lh[b], phb = lph[b];
                const double P  = (double)pp +
                                  (hb ? (double)rneed * (double)phb / (double)hb : 0.0);
                const double Cr = 2.0 * (double)k - P; // |A ∪ B| for this row
                s_crfx = (unsigned long long)(Cr * 1048576.0 + 0.5);
                break;
            }
            cum = nv;
            pp += lph[b];
        }
    }

    // rowtot (ce2 sum) for rows 0,1: lanes 0..63 of wave 0, fixed-tree reduce
    if (row < 2 && tid < 64) {
        double d = (double)rowpart[row * CHUNKS + tid];
        for (int o = 32; o > 0; o >>= 1) d += __shfl_down(d, o);
        if (tid == 0) s_rsum = d;
    }
    __syncthreads();

    if (tid == 0) {
        rowCfx[row] = s_crfx;
        if (row < 2) rowr01[row] = s_rsum;
        __threadfence();                               // make results device-visible
        const unsigned old = atomicAdd(ticket, 1u);
        if (old == NROWS - 1) {                        // last block: final reduction
            __threadfence();
            double C = 0.0;
            for (int r = 0; r < NROWS; ++r) C += (double)rowCfx[r];
            C *= (1.0 / 1048576.0);
            constexpr double LN2 = 0.6931471805599453;
            const double nL = (double)NROWS * (double)HW;
            const double r0 = rowr01[0] / (double)HW * LN2;
            const double r1 = rowr01[1] / (double)HW * LN2;
            outp[0] = (float)(((nL - C) * r0 + C * r1) / nL);
        }
    }
}

extern "C" void kernel_launch(void* const* d_in, const int* in_sizes, int n_in,
                              void* d_out, int out_size, void* d_ws, size_t ws_size,
                              hipStream_t stream) {
    const float* logits  = (const float*)d_in[0];
    const int*   targets = (const int*)d_in[1];
    float*       out     = (float*)d_out;
    char*        ws      = (char*)d_ws;

    zero_kernel<<<(int)(ZERO_LEN / (256 * 16)), 256, 0, stream>>>(
        (ulonglong2*)(ws + OFF_META));

    ce_hist_kernel<<<NROWS * CHUNKS, THREADS, 0, stream>>>(
        logits, targets,
        (float*)(ws + OFF_ROWPART),
        (unsigned long long*)(ws + OFF_HIST));

    select_kernel<<<NROWS, 256, 0, stream>>>(
        (const unsigned long long*)(ws + OFF_HIST),
        (const float*)(ws + OFF_ROWPART),
        (unsigned*)(ws + OFF_META),
        (unsigned long long*)(ws + OFF_META + 64),
        (double*)(ws + OFF_META + 320),
        out);
}

// Round 11
// 54.205 us; speedup vs baseline: 5.9708x; 1.0324x over previous
//
#include <hip/hip_runtime.h>

// Problem constants
constexpr int NROWS     = 32;
constexpr int HW        = 768 * 768;        // 589824 pixels per image
constexpr int CHUNKS    = 64;               // chunks per row in main pass
constexpr int CHUNK_PIX = HW / CHUNKS;      // 9216
constexpr int NB        = 4096;             // buckets over sortable margin bits
constexpr int THREADS   = 256;

// Workspace layout (bytes)
constexpr size_t OFF_ROWPART = 0;          // float[NROWS*CHUNKS] = 8 KB (fully overwritten each call)
constexpr size_t OFF_META    = 8192;       // zeroed: ticket u32 @0; rowCfx u64[32] @64; rowr01 double[2] @320
constexpr size_t OFF_HIST    = 16384;      // u64[NROWS*NB] = 1 MiB (zeroed)
constexpr size_t ZERO_LEN    = 8192 + (size_t)NROWS * NB * 8;   // 1056768 = 258*256*16

// Zero meta + packed histogram: 258 blocks x 256 threads x 16 B.
__global__ __launch_bounds__(256) void zero_kernel(ulonglong2* __restrict__ h)
{
    h[(size_t)blockIdx.x * 256 + threadIdx.x] = ulonglong2{0ull, 0ull};
}

// Pass 1: per (row, chunk) block. Branch-free streaming body:
//   ub  = bits(x0-x1) ^ (t<<31)                  (margin v; ce monotone-decreasing in v)
//   key = sortable(ub) >> 20                     (4096 buckets, ascending in v)
//   packed LDS atomic: low16 = all, high16 = positives (block px = 9216 < 2^16)
// ce2 (= ce/ln2) sums only for rows 0,1 (block-uniform branch) — all the output needs.
__global__ __launch_bounds__(THREADS) void ce_hist_kernel(
    const float* __restrict__ logits, const int* __restrict__ targets,
    float* __restrict__ rowpart, unsigned long long* __restrict__ hist)
{
    __shared__ unsigned lh[NB];
    __shared__ float    redf[THREADS / 64];

    const int blk   = blockIdx.x;
    const int row   = blk >> 6;      // / CHUNKS
    const int chunk = blk & 63;      // % CHUNKS

    for (int b = threadIdx.x; b < NB; b += THREADS) lh[b] = 0u;
    __syncthreads();

    const float* x0 = logits + (size_t)row * 2 * HW + (size_t)chunk * CHUNK_PIX;
    const float* x1 = x0 + HW;
    const int*   tp = targets + (size_t)row * HW + (size_t)chunk * CHUNK_PIX;
    const bool needsum = (row < 2);

    float lsum = 0.f;

    for (int p = threadIdx.x * 4; p < CHUNK_PIX; p += THREADS * 4) {
        const float4 a0 = *(const float4*)(x0 + p);
        const float4 a1 = *(const float4*)(x1 + p);
        const int4   t4 = *(const int4*)(tp + p);
        const float* v0 = (const float*)&a0;
        const float* v1 = (const float*)&a1;
        const int*   tv = (const int*)&t4;
#pragma unroll
        for (int j = 0; j < 4; ++j) {
            const unsigned t  = (unsigned)tv[j];
            const unsigned ub = __float_as_uint(v0[j] - v1[j]) ^ (t << 31); // margin bits
            if (needsum) {   // rows 0,1 only: ce2 = max(-w,0) + log2(1+2^-|w|)
                const float w = __uint_as_float(ub) * 1.4426950408889634f;
                lsum += fmaxf(-w, 0.f) + __log2f(1.f + exp2f(-fabsf(w)));
            }
            // sortable float transform: ascending key <=> ascending margin v
            const unsigned m   = (unsigned)((int)ub >> 31) | 0x80000000u;
            const unsigned key = (ub ^ m) >> 20;
            atomicAdd(&lh[key], 1u | (t << 16));
        }
    }

    // wave-reduce the ce2 sum
    for (int o = 32; o > 0; o >>= 1) lsum += __shfl_down(lsum, o);
    const int wid  = threadIdx.x >> 6;
    const int lane = threadIdx.x & 63;
    if (lane == 0) redf[wid] = lsum;
    __syncthreads();   // also orders all LDS histogram atomics before flush

    if (threadIdx.x == 0) {
        float s = 0.f;
        for (int w = 0; w < THREADS / 64; ++w) s += redf[w];
        rowpart[row * CHUNKS + chunk] = s;   // deterministic partial (0 for rows >= 2)
    }

    // flush packed histogram: one u64 global atomic per nonzero bucket
    for (int b = threadIdx.x; b < NB; b += THREADS) {
        const unsigned v = lh[b];
        if (v) {
            atomicAdd(&hist[(size_t)row * NB + b],
                      ((unsigned long long)(v & 0xFFFFu) << 32) | (v >> 16));
        }
    }
}

// Pass 2 (fused select + final): one block per row.
// pos = total positives; k = min(pos, HW-pos); B = k smallest margins (= k largest ce).
// Packed u64 Hillis-Steele scan (counts hi32, positives lo32) finds the threshold
// bucket + positives below it; proportional split inside it.
// Cr = |A ∪ B| = 2k - (#positives in B), stored fixed-point x2^20 (exact, deterministic).
// The last block (atomic ticket) reduces all rows and writes the scalar output.
__global__ __launch_bounds__(256) void select_kernel(
    const unsigned long long* __restrict__ hist,
    const float* __restrict__ rowpart,
    unsigned* __restrict__ ticket,
    unsigned long long* __restrict__ rowCfx,
    double* __restrict__ rowr01,
    float* __restrict__ outp)
{
    __shared__ unsigned lh[NB];
    __shared__ unsigned lph[NB];
    __shared__ unsigned long long sc[256];
    __shared__ unsigned long long s_crfx;
    __shared__ double s_rsum;

    const int row = blockIdx.x;
    const int tid = threadIdx.x;

    for (int b = tid; b < NB; b += 256) {
        const unsigned long long v = hist[(size_t)row * NB + b];
        lh[b]  = (unsigned)(v >> 32);   // all
        lph[b] = (unsigned)v;           // positives
    }
    if (tid == 0) s_crfx = 0ull;
    __syncthreads();

    // per-thread 16-bucket segment sums, packed
    const int base = tid * 16;
    unsigned ssum = 0u, psum = 0u;
#pragma unroll
    for (int j = 0; j < 16; ++j) { ssum += lh[base + j]; psum += lph[base + j]; }
    sc[tid] = ((unsigned long long)ssum << 32) | psum;
    __syncthreads();

    // inclusive Hillis-Steele scan over 256 threads (no cross-carry: both sums < 2^32)
#pragma unroll
    for (int off = 1; off < 256; off <<= 1) {
        const unsigned long long v = sc[tid];
        const unsigned long long a = (tid >= off) ? sc[tid - off] : 0ull;
        __syncthreads();
        sc[tid] = v + a;
        __syncthreads();
    }

    const unsigned pos   = (unsigned)sc[255];          // total positives
    const unsigned k     = min(pos, (unsigned)HW - pos);
    const unsigned long long incl = sc[tid];
    const unsigned cexcl = (unsigned)(incl >> 32) - ssum;
    const unsigned pexcl = (unsigned)incl - psum;

    if (k > 0 && cexcl < k && cexcl + ssum >= k) {     // exactly one thread matches
        unsigned cum = cexcl, pp = pexcl;
#pragma unroll
        for (int j = 0; j < 16; ++j) {
            const int b = base + j;
            const unsigned nv = cum + lh[b];
            if (nv >= k) {
                const unsigned rneed = k - cum;        // 1..lh[b]
                const unsigned hb = lh[b], phb = lph[b];
                const double P  = (double)pp +
                                  (hb ? (double)rneed * (double)phb / (double)hb : 0.0);
                const double Cr = 2.0 * (double)k - P; // |A ∪ B| for this row
                s_crfx = (unsigned long long)(Cr * 1048576.0 + 0.5);
                break;
            }
            cum = nv;
            pp += lph[b];
        }
    }

    // rowtot (ce2 sum) for rows 0,1: lanes 0..63 of wave 0, fixed-tree reduce
    if (row < 2 && tid < 64) {
        double d = (double)rowpart[row * CHUNKS + tid];
        for (int o = 32; o > 0; o >>= 1) d += __shfl_down(d, o);
        if (tid == 0) s_rsum = d;
    }
    __syncthreads();

    if (tid == 0) {
        rowCfx[row] = s_crfx;
        if (row < 2) rowr01[row] = s_rsum;
        __threadfence();                               // make results device-visible
        const unsigned old = atomicAdd(ticket, 1u);
        if (old == NROWS - 1) {                        // last block: final reduction
            __threadfence();
            double C = 0.0;
            for (int r = 0; r < NROWS; ++r) C += (double)rowCfx[r];
            C *= (1.0 / 1048576.0);
            constexpr double LN2 = 0.6931471805599453;
            const double nL = (double)NROWS * (double)HW;
            const double r0 = rowr01[0] / (double)HW * LN2;
            const double r1 = rowr01[1] / (double)HW * LN2;
            outp[0] = (float)(((nL - C) * r0 + C * r1) / nL);
        }
    }
}

extern "C" void kernel_launch(void* const* d_in, const int* in_sizes, int n_in,
                              void* d_out, int out_size, void* d_ws, size_t ws_size,
                              hipStream_t stream) {
    const float* logits  = (const float*)d_in[0];
    const int*   targets = (const int*)d_in[1];
    float*       out     = (float*)d_out;
    char*        ws      = (char*)d_ws;

    zero_kernel<<<(int)(ZERO_LEN / (256 * 16)), 256, 0, stream>>>(
        (ulonglong2*)(ws + OFF_META));

    ce_hist_kernel<<<NROWS * CHUNKS, THREADS, 0, stream>>>(
        logits, targets,
        (float*)(ws + OFF_ROWPART),
        (unsigned long long*)(ws + OFF_HIST));

    select_kernel<<<NROWS, 256, 0, stream>>>(
        (const unsigned long long*)(ws + OFF_HIST),
        (const float*)(ws + OFF_ROWPART),
        (unsigned*)(ws + OFF_META),
        (unsigned long long*)(ws + OFF_META + 64),
        (double*)(ws + OFF_META + 320),
        out);
}